// Round 1
// baseline (2857.808 us; speedup 1.0000x reference)
//
#include <hip/hip_runtime.h>
#include <math.h>

#define EPSV 1e-5f

__device__ __forceinline__ float silu_f(float v) { return v / (1.f + __expf(-v)); }

// ---------------------------------------------------------------------------
// Direct 3x3 SAME conv + BN(eval) + SiLU.  One wave (64 threads) per (n,co,h)
// row; weights are wave-uniform -> scalar loads.
// ---------------------------------------------------------------------------
template <int CIN>
__global__ __launch_bounds__(64) void conv3_bn_silu(
    const float* __restrict__ x, const float* __restrict__ wgt,
    const float* __restrict__ gg, const float* __restrict__ bb,
    const float* __restrict__ mm, const float* __restrict__ vv,
    float* __restrict__ out, int Cout) {
  const int wx = threadIdx.x;        // 0..63  (W)
  const int co = blockIdx.x;
  const int h  = blockIdx.y;
  const int n  = blockIdx.z;
  const float* xn = x + (size_t)n * CIN * 4096;
  const float* wp = wgt + (size_t)co * CIN * 9;
  float acc = 0.f;
  const int ym = h - 1, yp = h + 1;
  for (int ci = 0; ci < CIN; ci++) {
    const float* xc = xn + ci * 4096;
    const float* wq = wp + ci * 9;
    float w0 = wq[0], w1 = wq[1], w2 = wq[2];
    float w3 = wq[3], w4 = wq[4], w5 = wq[5];
    float w6 = wq[6], w7 = wq[7], w8 = wq[8];
    if (ym >= 0) {
      const float* r = xc + ym * 64;
      if (wx > 0)  acc += r[wx - 1] * w0;
      acc += r[wx] * w1;
      if (wx < 63) acc += r[wx + 1] * w2;
    }
    {
      const float* r = xc + h * 64;
      if (wx > 0)  acc += r[wx - 1] * w3;
      acc += r[wx] * w4;
      if (wx < 63) acc += r[wx + 1] * w5;
    }
    if (yp < 64) {
      const float* r = xc + yp * 64;
      if (wx > 0)  acc += r[wx - 1] * w6;
      acc += r[wx] * w7;
      if (wx < 63) acc += r[wx + 1] * w8;
    }
  }
  float s = gg[co] * rsqrtf(vv[co] + EPSV);
  float val = acc * s + (bb[co] - mm[co] * s);
  out[(((size_t)n * Cout + co) * 64 + h) * 64 + wx] = silu_f(val);
}

// ---------------------------------------------------------------------------
// Tiled fp32 GEMM:  out(R x Co) = A(R x K) @ W(Co x K)^T + bias, with epilogue.
//   A_NCHW: A element (row,k) at A[n*K*4096 + k*4096 + p], row = n*4096+p
//   EPI 0: plain (+bias)
//   EPI 1: +bias then BN3 (e0..e3 = g,b,m,v)
//   EPI 2: +bias then SiLU
//   EPI 3: +bias, add e0 (x NCHW) + e1 (y2 NCHW), store NCHW (Co==256)
// Block 16x16 threads, 64x64 tile, BK=16, each thread 4x4 outputs.
// ---------------------------------------------------------------------------
template <int EPI, bool A_NCHW>
__global__ __launch_bounds__(256) void gemm_ep(
    const float* __restrict__ A, const float* __restrict__ Wt,
    const float* __restrict__ bias, int K, int Co,
    float* __restrict__ out,
    const float* __restrict__ e0, const float* __restrict__ e1,
    const float* __restrict__ e2, const float* __restrict__ e3) {
  __shared__ float As[16][65];
  __shared__ float Bs[16][66];
  const int t  = threadIdx.y * 16 + threadIdx.x;
  const int rb = blockIdx.y * 64;
  const int cb = blockIdx.x * 64;
  float acc[4][4] = {};
  for (int kb = 0; kb < K; kb += 16) {
    if (A_NCHW) {
      int row = t & 63, kq = t >> 6;  // kq 0..3
      int gr = rb + row;
      int n = gr >> 12, p = gr & 4095;
      const float* ap = A + (size_t)n * K * 4096 + p;
#pragma unroll
      for (int i = 0; i < 4; i++) {
        int k = kq + i * 4;
        As[k][row] = ap[(size_t)(kb + k) * 4096];
      }
    } else {
      int k = t & 15, r0 = t >> 4;
#pragma unroll
      for (int i = 0; i < 4; i++) {
        int row = r0 + i * 16;
        As[k][row] = A[(size_t)(rb + row) * K + kb + k];
      }
    }
    {
      int k = t & 15, c0 = t >> 4;
#pragma unroll
      for (int i = 0; i < 4; i++) {
        int co = c0 + i * 16;
        Bs[k][co] = (cb + co < Co) ? Wt[(size_t)(cb + co) * K + kb + k] : 0.f;
      }
    }
    __syncthreads();
#pragma unroll
    for (int kk = 0; kk < 16; kk++) {
      float av[4], bv[4];
#pragma unroll
      for (int i = 0; i < 4; i++) av[i] = As[kk][threadIdx.y * 4 + i];
#pragma unroll
      for (int j = 0; j < 4; j++) bv[j] = Bs[kk][threadIdx.x * 4 + j];
#pragma unroll
      for (int i = 0; i < 4; i++)
#pragma unroll
        for (int j = 0; j < 4; j++) acc[i][j] += av[i] * bv[j];
    }
    __syncthreads();
  }
#pragma unroll
  for (int j = 0; j < 4; j++) {
    int gc = cb + threadIdx.x * 4 + j;
    if (gc >= Co) continue;
    float bval = bias[gc];
    float s = 0.f, tt = 0.f;
    if (EPI == 1) {
      s = e0[gc] * rsqrtf(e3[gc] + EPSV);
      tt = e1[gc] - e2[gc] * s;
    }
#pragma unroll
    for (int i = 0; i < 4; i++) {
      int gr = rb + threadIdx.y * 4 + i;
      float v = acc[i][j] + bval;
      if (EPI == 1) v = v * s + tt;
      if (EPI == 2) v = silu_f(v);
      if (EPI == 3) {
        int n = gr >> 12, p = gr & 4095;
        size_t idx = ((size_t)(n * 256 + gc)) * 4096 + p;
        out[idx] = v + e0[idx] + e1[idx];
      } else {
        out[(size_t)gr * Co + gc] = v;
      }
    }
  }
}

// ---------------------------------------------------------------------------
// DCNv4 core.  value: (N, HW, 256) row-major, channel = g*32+c.
// om: (N, HW, 216), per group g: [0..17]=offset pairs (x,y), [18..26]=mask.
// One thread per (n,p,g,c); block = 256 threads = one pixel (all 8 groups).
// ---------------------------------------------------------------------------
__global__ __launch_bounds__(256) void dcn_core(
    const float* __restrict__ value, const float* __restrict__ om,
    float* __restrict__ out) {
  const int p = blockIdx.x;
  const int n = blockIdx.y;
  const int c = threadIdx.x & 31;
  const int g = threadIdx.x >> 5;
  const int h0 = p >> 6, w0 = p & 63;
  const float* omp = om + ((size_t)(n * 4096 + p)) * 216 + g * 27;
  const float* vb = value + ((size_t)n * 4096) * 256 + g * 32 + c;
  float acc = 0.f;
#pragma unroll
  for (int k = 0; k < 9; k++) {
    float ox = omp[2 * k], oy = omp[2 * k + 1], mk = omp[18 + k];
    float px = (float)(w0 + (k % 3) - 1) + ox;
    float py = (float)(h0 + (k / 3) - 1) + oy;
    float x0f = floorf(px), y0f = floorf(py);
    float lx = px - x0f, ly = py - y0f;
    int x0 = (int)x0f, y0 = (int)y0f;
    int x1 = x0 + 1, y1 = y0 + 1;
    float w00 = (1.f - ly) * (1.f - lx), w01 = (1.f - ly) * lx;
    float w10 = ly * (1.f - lx), w11 = ly * lx;
    bool vx0 = (x0 >= 0) & (x0 < 64), vx1 = (x1 >= 0) & (x1 < 64);
    bool vy0 = (y0 >= 0) & (y0 < 64), vy1 = (y1 >= 0) & (y1 < 64);
    int cx0 = min(max(x0, 0), 63), cx1 = min(max(x1, 0), 63);
    int cy0 = min(max(y0, 0), 63), cy1 = min(max(y1, 0), 63);
    float v00 = vb[(size_t)(cy0 * 64 + cx0) * 256];
    float v01 = vb[(size_t)(cy0 * 64 + cx1) * 256];
    float v10 = vb[(size_t)(cy1 * 64 + cx0) * 256];
    float v11 = vb[(size_t)(cy1 * 64 + cx1) * 256];
    float sm = v00 * (w00 * (vy0 && vx0)) + v01 * (w01 * (vy0 && vx1)) +
               v10 * (w10 * (vy1 && vx0)) + v11 * (w11 * (vy1 && vx1));
    acc += mk * sm;
  }
  out[((size_t)(n * 4096 + p)) * 256 + g * 32 + c] = acc;
}

// ---------------------------------------------------------------------------
extern "C" void kernel_launch(void* const* d_in, const int* in_sizes, int n_in,
                              void* d_out, int out_size, void* d_ws,
                              size_t ws_size, hipStream_t stream) {
  const float* x      = (const float*)d_in[0];
  const float* cv1_w  = (const float*)d_in[1];
  const float* cv1_g  = (const float*)d_in[2];
  const float* cv1_b  = (const float*)d_in[3];
  const float* cv1_m  = (const float*)d_in[4];
  const float* cv1_v  = (const float*)d_in[5];
  const float* cv2_w  = (const float*)d_in[6];
  const float* cv2_g  = (const float*)d_in[7];
  const float* cv2_b  = (const float*)d_in[8];
  const float* cv2_m  = (const float*)d_in[9];
  const float* cv2_v  = (const float*)d_in[10];
  const float* val_w  = (const float*)d_in[11];
  const float* val_b  = (const float*)d_in[12];
  const float* om_w   = (const float*)d_in[13];
  const float* om_b   = (const float*)d_in[14];
  const float* outp_w = (const float*)d_in[15];
  const float* outp_b = (const float*)d_in[16];
  const float* bn3_g  = (const float*)d_in[17];
  const float* bn3_b  = (const float*)d_in[18];
  const float* bn3_m  = (const float*)d_in[19];
  const float* bn3_v  = (const float*)d_in[20];
  const float* pw1_w  = (const float*)d_in[21];
  const float* pw1_b  = (const float*)d_in[22];
  const float* pw2_w  = (const float*)d_in[23];
  const float* pw2_b  = (const float*)d_in[24];

  float* out = (float*)d_out;
  float* ws = (float*)d_ws;
  // workspace layout (floats):
  float* y2b  = ws;              // 4,194,304   y2 (N,256,HW) NCHW
  float* valb = ws + 4194304;    // 4,194,304   value (N,HW,256); later d1
  float* omb  = ws + 8388608;    // 3,538,944   om (N,HW,216)
  float* dcno = ws + 11927552;   // 4,194,304   dcn core out; y1 aliases here
  float* y1b  = dcno;            //             y1 (N,128,HW), dead before dcno
  float* p1   = ws + 16121856;   // 12,582,912  pw1 out (N,HW,768)
  // total: 28,704,768 floats = 114.8 MB

  dim3 b64(64), tb(16, 16);

  // y path
  conv3_bn_silu<256><<<dim3(128, 64, 4), b64, 0, stream>>>(
      x, cv1_w, cv1_g, cv1_b, cv1_m, cv1_v, y1b, 128);
  conv3_bn_silu<128><<<dim3(256, 64, 4), b64, 0, stream>>>(
      y1b, cv2_w, cv2_g, cv2_b, cv2_m, cv2_v, y2b, 256);

  // dcn path
  gemm_ep<0, true><<<dim3(4, 256), tb, 0, stream>>>(
      x, val_w, val_b, 256, 256, valb, nullptr, nullptr, nullptr, nullptr);
  gemm_ep<0, true><<<dim3(4, 256), tb, 0, stream>>>(
      x, om_w, om_b, 256, 216, omb, nullptr, nullptr, nullptr, nullptr);
  dcn_core<<<dim3(4096, 4), 256, 0, stream>>>(valb, omb, dcno);
  gemm_ep<1, false><<<dim3(4, 256), tb, 0, stream>>>(
      dcno, outp_w, outp_b, 256, 256, valb, bn3_g, bn3_b, bn3_m, bn3_v);
  gemm_ep<2, false><<<dim3(12, 256), tb, 0, stream>>>(
      valb, pw1_w, pw1_b, 256, 768, p1, nullptr, nullptr, nullptr, nullptr);
  gemm_ep<3, false><<<dim3(4, 256), tb, 0, stream>>>(
      p1, pw2_w, pw2_b, 768, 256, out, x, y2b, nullptr, nullptr);
}

// Round 2
// 366.775 us; speedup vs baseline: 7.7917x; 7.7917x over previous
//
#include <hip/hip_runtime.h>
#include <math.h>

typedef __attribute__((ext_vector_type(8))) __bf16 bf16x8;
typedef __attribute__((ext_vector_type(8))) unsigned short us8;
typedef __attribute__((ext_vector_type(4))) float f32x4;
typedef unsigned int uint32;

#define EPSV 1e-5f

__device__ __forceinline__ float silu_f(float v) { return v / (1.f + __expf(-v)); }

__device__ __forceinline__ unsigned short f2bf(float f) {
  uint32 u = __builtin_bit_cast(uint32, f);
  u += 0x7fffu + ((u >> 16) & 1u);   // RNE
  return (unsigned short)(u >> 16);
}
__device__ __forceinline__ float bf2f(unsigned short h) {
  uint32 u = ((uint32)h) << 16;
  return __builtin_bit_cast(float, u);
}
__device__ __forceinline__ bf16x8 bfz() {
  bf16x8 v;
#pragma unroll
  for (int j = 0; j < 8; j++) v[j] = (__bf16)0.0f;
  return v;
}

// ---------------------------------------------------------------------------
// NCHW f32 -> NHWC bf16 tokens (N,4096,256), via LDS transpose.
// grid (64 p-tiles, 4 c-tiles, N), block 256.
// ---------------------------------------------------------------------------
__global__ __launch_bounds__(256) void nchw_to_tok(const float* __restrict__ x,
                                                   unsigned short* __restrict__ xt) {
  __shared__ float lds[64][65];
  const int p0 = blockIdx.x * 64, c0 = blockIdx.y * 64, n = blockIdx.z;
  const int t = threadIdx.x;
  const int pp = t & 63, ccb = t >> 6;
  const float* xb = x + ((size_t)n * 256 + c0) * 4096 + p0;
#pragma unroll
  for (int i = 0; i < 16; i++) {
    int cc = ccb * 16 + i;
    lds[pp][cc] = xb[(size_t)cc * 4096 + pp];
  }
  __syncthreads();
#pragma unroll
  for (int i = 0; i < 2; i++) {
    int pp2 = (t >> 3) + i * 32;
    int c8 = (t & 7) * 8;
    us8 v;
#pragma unroll
    for (int j = 0; j < 8; j++) v[j] = f2bf(lds[pp2][c8 + j]);
    *(us8*)&xt[((size_t)(n * 4096 + p0 + pp2)) * 256 + c0 + c8] = v;
  }
}

// ---------------------------------------------------------------------------
// out = x + y2 + d  (tokens bf16 -> NCHW f32), via LDS transpose.
// ---------------------------------------------------------------------------
__global__ __launch_bounds__(256) void fuse_out_k(
    const float* __restrict__ x, const unsigned short* __restrict__ y2t,
    const unsigned short* __restrict__ dt, float* __restrict__ out) {
  __shared__ float lds[64][65];
  const int p0 = blockIdx.x * 64, c0 = blockIdx.y * 64, n = blockIdx.z;
  const int t = threadIdx.x;
#pragma unroll
  for (int i = 0; i < 2; i++) {
    int pp = (t >> 3) + i * 32;
    int c8 = (t & 7) * 8;
    size_t base = ((size_t)(n * 4096 + p0 + pp)) * 256 + c0 + c8;
    us8 a = *(const us8*)&y2t[base];
    us8 b = *(const us8*)&dt[base];
#pragma unroll
    for (int j = 0; j < 8; j++) lds[pp][c8 + j] = bf2f(a[j]) + bf2f(b[j]);
  }
  __syncthreads();
  const int pp2 = t & 63, ccb = t >> 6;
  const size_t nco = ((size_t)n * 256 + c0) * 4096 + p0;
#pragma unroll
  for (int i = 0; i < 16; i++) {
    int cc = ccb * 16 + i;
    size_t idx = nco + (size_t)cc * 4096 + pp2;
    out[idx] = x[idx] + lds[pp2][cc];
  }
}

// ---------------------------------------------------------------------------
// Weight conversions.
// conv: (Co,Ci,3,3) f32 -> (Co, 9*Ci) bf16 with k = tap*Ci + ci
// ---------------------------------------------------------------------------
__global__ void cvt_conv_w(const float* __restrict__ w, unsigned short* __restrict__ o,
                           int Co, int Ci) {
  int idx = blockIdx.x * 256 + threadIdx.x;
  int tot = Co * 9 * Ci;
  if (idx >= tot) return;
  int ci = idx % Ci;
  int r = idx / Ci;
  int tap = r % 9;
  int co = r / 9;
  o[idx] = f2bf(w[((size_t)co * Ci + ci) * 9 + tap]);
}

__global__ void cvt_f32_bf16(const float* __restrict__ w, unsigned short* __restrict__ o,
                             int nel) {
  int idx = blockIdx.x * 256 + threadIdx.x;
  if (idx < nel) o[idx] = f2bf(w[idx]);
}

// ---------------------------------------------------------------------------
// Unified bf16 MFMA GEMM, 128x128 tile, 4 waves, BK=64.
//   A: tokens (16384, K) bf16; CONV (CIN>0): K = 9*CIN, implicit im2col with
//      tap shift + border mask (tap uniform per 64-k block since 64|CIN).
//   B: (Co, K) bf16 row-major (i.e. W, used as B^T).
// LDS layout is fragment-major: 16B chunk id = ((msub*2+ks)*64 + kg*16+row16)
// so a wave's frag read is lane-linear (conflict-free), as is the stage write.
// EPI: 0 = bias->bf16 | 1 = bias->f32 | 2 = BN+SiLU->bf16 (no bias)
//      3 = bias+BN->bf16 | 4 = bias+SiLU->bf16
// ---------------------------------------------------------------------------
template <int EPI, int CIN>
__global__ __launch_bounds__(256) void mfma_gemm(
    const unsigned short* __restrict__ A, const unsigned short* __restrict__ Bw,
    const float* __restrict__ bias, int K, int Co, void* __restrict__ outv,
    const float* __restrict__ e0, const float* __restrict__ e1,
    const float* __restrict__ e2, const float* __restrict__ e3) {
  __shared__ bf16x8 Asm[1024];  // 16 KB
  __shared__ bf16x8 Bsm[1024];  // 16 KB
  const int t = threadIdx.x;
  const int lane = t & 63;
  const int wv = t >> 6;
  const int wr = wv >> 1, wc = wv & 1;
  const int rb = blockIdx.y * 128, cb = blockIdx.x * 128;

  f32x4 acc[4][4];
#pragma unroll
  for (int i = 0; i < 4; i++)
#pragma unroll
    for (int j = 0; j < 4; j++) acc[i][j] = (f32x4){0.f, 0.f, 0.f, 0.f};

  for (int kb = 0; kb < K; kb += 64) {
    // ---- stage A (1024 chunks of 8 bf16)
#pragma unroll
    for (int i = 0; i < 4; i++) {
      int c = t + 256 * i;
      int row16 = c & 15, kg = (c >> 4) & 3, ks = (c >> 6) & 1, msub = c >> 7;
      int row = msub * 16 + row16;
      int koff = ks * 32 + kg * 8;
      bf16x8 v = bfz();
      if constexpr (CIN > 0) {
        int tap = kb / CIN, ci0 = kb % CIN;
        int dy = tap / 3 - 1, dx = tap % 3 - 1;
        int grow = rb + row;
        int n = grow >> 12, p = grow & 4095;
        int h = (p >> 6) + dy, w = (p & 63) + dx;
        if (((unsigned)h < 64u) && ((unsigned)w < 64u))
          v = *(const bf16x8*)&A[((size_t)(n * 4096 + h * 64 + w)) * CIN + ci0 + koff];
      } else {
        v = *(const bf16x8*)&A[(size_t)(rb + row) * K + kb + koff];
      }
      Asm[c] = v;
    }
    // ---- stage B
#pragma unroll
    for (int i = 0; i < 4; i++) {
      int c = t + 256 * i;
      int col16 = c & 15, kg = (c >> 4) & 3, ks = (c >> 6) & 1, csub = c >> 7;
      int col = cb + csub * 16 + col16;
      int koff = ks * 32 + kg * 8;
      bf16x8 v = bfz();
      if (col < Co) v = *(const bf16x8*)&Bw[(size_t)col * K + kb + koff];
      Bsm[c] = v;
    }
    __syncthreads();
    // ---- compute: 2 k-steps of 32
#pragma unroll
    for (int ks = 0; ks < 2; ks++) {
      bf16x8 af[4], bfr[4];
#pragma unroll
      for (int mi = 0; mi < 4; mi++) af[mi] = Asm[((wr * 4 + mi) * 2 + ks) * 64 + lane];
#pragma unroll
      for (int ni = 0; ni < 4; ni++) bfr[ni] = Bsm[((wc * 4 + ni) * 2 + ks) * 64 + lane];
#pragma unroll
      for (int mi = 0; mi < 4; mi++)
#pragma unroll
        for (int ni = 0; ni < 4; ni++)
          acc[mi][ni] = __builtin_amdgcn_mfma_f32_16x16x32_bf16(af[mi], bfr[ni],
                                                                acc[mi][ni], 0, 0, 0);
    }
    __syncthreads();
  }

  // ---- epilogue.  C/D: col = lane&15, row = (lane>>4)*4 + reg
  const int lr = lane & 15, kg4 = (lane >> 4) * 4;
#pragma unroll
  for (int mi = 0; mi < 4; mi++) {
#pragma unroll
    for (int ni = 0; ni < 4; ni++) {
      int gcol = cb + wc * 64 + ni * 16 + lr;
      if (gcol < Co) {
        float bval = (EPI == 2) ? 0.f : bias[gcol];
        float s = 1.f, tt = 0.f;
        if (EPI == 2 || EPI == 3) {
          s = e0[gcol] * rsqrtf(e3[gcol] + EPSV);
          tt = e1[gcol] - e2[gcol] * s;
        }
#pragma unroll
        for (int j = 0; j < 4; j++) {
          int grow = rb + wr * 64 + mi * 16 + kg4 + j;
          float v = acc[mi][ni][j] + bval;
          if (EPI == 2) v = silu_f(v * s + tt);
          if (EPI == 3) v = v * s + tt;
          if (EPI == 4) v = silu_f(v);
          if (EPI == 1)
            ((float*)outv)[(size_t)grow * Co + gcol] = v;
          else
            ((unsigned short*)outv)[(size_t)grow * Co + gcol] = f2bf(v);
        }
      }
    }
  }
}

// ---------------------------------------------------------------------------
// DCNv4 core.  value: bf16 tokens (N,4096,256), om: f32 tokens (N,4096,216).
// out: bf16 tokens. One thread per (n,p,g,c).
// ---------------------------------------------------------------------------
__global__ __launch_bounds__(256) void dcn_core(
    const unsigned short* __restrict__ value, const float* __restrict__ om,
    unsigned short* __restrict__ out) {
  const int p = blockIdx.x;
  const int n = blockIdx.y;
  const int c = threadIdx.x & 31;
  const int g = threadIdx.x >> 5;
  const int h0 = p >> 6, w0 = p & 63;
  const float* omp = om + ((size_t)(n * 4096 + p)) * 216 + g * 27;
  const unsigned short* vb = value + ((size_t)(n * 4096)) * 256 + g * 32 + c;
  float acc = 0.f;
#pragma unroll
  for (int k = 0; k < 9; k++) {
    float ox = omp[2 * k], oy = omp[2 * k + 1], mk = omp[18 + k];
    float px = (float)(w0 + (k % 3) - 1) + ox;
    float py = (float)(h0 + (k / 3) - 1) + oy;
    float x0f = floorf(px), y0f = floorf(py);
    float lx = px - x0f, ly = py - y0f;
    int x0 = (int)x0f, y0 = (int)y0f;
    int x1 = x0 + 1, y1 = y0 + 1;
    float w00 = (1.f - ly) * (1.f - lx), w01 = (1.f - ly) * lx;
    float w10 = ly * (1.f - lx), w11 = ly * lx;
    bool vx0 = (x0 >= 0) & (x0 < 64), vx1 = (x1 >= 0) & (x1 < 64);
    bool vy0 = (y0 >= 0) & (y0 < 64), vy1 = (y1 >= 0) & (y1 < 64);
    int cx0 = min(max(x0, 0), 63), cx1 = min(max(x1, 0), 63);
    int cy0 = min(max(y0, 0), 63), cy1 = min(max(y1, 0), 63);
    float v00 = bf2f(vb[(size_t)(cy0 * 64 + cx0) * 256]);
    float v01 = bf2f(vb[(size_t)(cy0 * 64 + cx1) * 256]);
    float v10 = bf2f(vb[(size_t)(cy1 * 64 + cx0) * 256]);
    float v11 = bf2f(vb[(size_t)(cy1 * 64 + cx1) * 256]);
    float sm = v00 * (w00 * (vy0 && vx0)) + v01 * (w01 * (vy0 && vx1)) +
               v10 * (w10 * (vy1 && vx0)) + v11 * (w11 * (vy1 && vx1));
    acc += mk * sm;
  }
  out[((size_t)(n * 4096 + p)) * 256 + g * 32 + c] = f2bf(acc);
}

// ---------------------------------------------------------------------------
extern "C" void kernel_launch(void* const* d_in, const int* in_sizes, int n_in,
                              void* d_out, int out_size, void* d_ws,
                              size_t ws_size, hipStream_t stream) {
  const float* x      = (const float*)d_in[0];
  const float* cv1_w  = (const float*)d_in[1];
  const float* cv1_g  = (const float*)d_in[2];
  const float* cv1_b  = (const float*)d_in[3];
  const float* cv1_m  = (const float*)d_in[4];
  const float* cv1_v  = (const float*)d_in[5];
  const float* cv2_w  = (const float*)d_in[6];
  const float* cv2_g  = (const float*)d_in[7];
  const float* cv2_b  = (const float*)d_in[8];
  const float* cv2_m  = (const float*)d_in[9];
  const float* cv2_v  = (const float*)d_in[10];
  const float* val_w  = (const float*)d_in[11];
  const float* val_b  = (const float*)d_in[12];
  const float* om_w   = (const float*)d_in[13];
  const float* om_b   = (const float*)d_in[14];
  const float* outp_w = (const float*)d_in[15];
  const float* outp_b = (const float*)d_in[16];
  const float* bn3_g  = (const float*)d_in[17];
  const float* bn3_b  = (const float*)d_in[18];
  const float* bn3_m  = (const float*)d_in[19];
  const float* bn3_v  = (const float*)d_in[20];
  const float* pw1_w  = (const float*)d_in[21];
  const float* pw1_b  = (const float*)d_in[22];
  const float* pw2_w  = (const float*)d_in[23];
  const float* pw2_b  = (const float*)d_in[24];
  float* out = (float*)d_out;

  char* w = (char*)d_ws;
  auto alloc = [&](size_t bytes) {
    char* p = w;
    w += (bytes + 255) & ~(size_t)255;
    return p;
  };
  unsigned short* xt    = (unsigned short*)alloc(16384ull * 256 * 2);
  unsigned short* y1t   = (unsigned short*)alloc(16384ull * 128 * 2);
  unsigned short* y2t   = (unsigned short*)alloc(16384ull * 256 * 2);
  unsigned short* valt  = (unsigned short*)alloc(16384ull * 256 * 2);
  float*          omf   = (float*)alloc(16384ull * 216 * 4);
  unsigned short* dcnt  = (unsigned short*)alloc(16384ull * 256 * 2);
  unsigned short* d1t   = (unsigned short*)alloc(16384ull * 256 * 2);
  unsigned short* p1t   = (unsigned short*)alloc(16384ull * 768 * 2);
  unsigned short* dt    = (unsigned short*)alloc(16384ull * 256 * 2);
  unsigned short* wc1   = (unsigned short*)alloc(128ull * 2304 * 2);
  unsigned short* wc2   = (unsigned short*)alloc(256ull * 1152 * 2);
  unsigned short* wval  = (unsigned short*)alloc(256ull * 256 * 2);
  unsigned short* wom   = (unsigned short*)alloc(216ull * 256 * 2);
  unsigned short* woutp = (unsigned short*)alloc(256ull * 256 * 2);
  unsigned short* wpw1  = (unsigned short*)alloc(768ull * 256 * 2);
  unsigned short* wpw2  = (unsigned short*)alloc(256ull * 768 * 2);

  // conversions
  nchw_to_tok<<<dim3(64, 4, 4), 256, 0, stream>>>(x, xt);
  cvt_conv_w<<<(128 * 2304 + 255) / 256, 256, 0, stream>>>(cv1_w, wc1, 128, 256);
  cvt_conv_w<<<(256 * 1152 + 255) / 256, 256, 0, stream>>>(cv2_w, wc2, 256, 128);
  cvt_f32_bf16<<<(65536 + 255) / 256, 256, 0, stream>>>(val_w, wval, 65536);
  cvt_f32_bf16<<<(55296 + 255) / 256, 256, 0, stream>>>(om_w, wom, 55296);
  cvt_f32_bf16<<<(65536 + 255) / 256, 256, 0, stream>>>(outp_w, woutp, 65536);
  cvt_f32_bf16<<<(196608 + 255) / 256, 256, 0, stream>>>(pw1_w, wpw1, 196608);
  cvt_f32_bf16<<<(196608 + 255) / 256, 256, 0, stream>>>(pw2_w, wpw2, 196608);

  // y path (convs as implicit GEMM)
  mfma_gemm<2, 256><<<dim3(1, 128), 256, 0, stream>>>(
      xt, wc1, nullptr, 2304, 128, y1t, cv1_g, cv1_b, cv1_m, cv1_v);
  mfma_gemm<2, 128><<<dim3(2, 128), 256, 0, stream>>>(
      y1t, wc2, nullptr, 1152, 256, y2t, cv2_g, cv2_b, cv2_m, cv2_v);

  // dcn path
  mfma_gemm<0, 0><<<dim3(2, 128), 256, 0, stream>>>(
      xt, wval, val_b, 256, 256, valt, nullptr, nullptr, nullptr, nullptr);
  mfma_gemm<1, 0><<<dim3(2, 128), 256, 0, stream>>>(
      xt, wom, om_b, 256, 216, omf, nullptr, nullptr, nullptr, nullptr);
  dcn_core<<<dim3(4096, 4), 256, 0, stream>>>(valt, omf, dcnt);
  mfma_gemm<3, 0><<<dim3(2, 128), 256, 0, stream>>>(
      dcnt, woutp, outp_b, 256, 256, d1t, bn3_g, bn3_b, bn3_m, bn3_v);
  mfma_gemm<4, 0><<<dim3(6, 128), 256, 0, stream>>>(
      d1t, wpw1, pw1_b, 256, 768, p1t, nullptr, nullptr, nullptr, nullptr);
  mfma_gemm<0, 0><<<dim3(2, 128), 256, 0, stream>>>(
      p1t, wpw2, pw2_b, 768, 256, dt, nullptr, nullptr, nullptr, nullptr);

  // out = x + y2 + d
  fuse_out_k<<<dim3(64, 4, 4), 256, 0, stream>>>(x, y2t, dt, out);
}

// Round 3
// 246.755 us; speedup vs baseline: 11.5815x; 1.4864x over previous
//
#include <hip/hip_runtime.h>
#include <math.h>

typedef __attribute__((ext_vector_type(8))) __bf16 bf16x8;
typedef __attribute__((ext_vector_type(8))) unsigned short us8;
typedef __attribute__((ext_vector_type(4))) float f32x4;
typedef unsigned int uint32;

#define EPSV 1e-5f

__device__ __forceinline__ float silu_f(float v) { return v / (1.f + __expf(-v)); }

__device__ __forceinline__ unsigned short f2bf(float f) {
  uint32 u = __builtin_bit_cast(uint32, f);
  u += 0x7fffu + ((u >> 16) & 1u);   // RNE
  return (unsigned short)(u >> 16);
}
__device__ __forceinline__ float bf2f(unsigned short h) {
  uint32 u = ((uint32)h) << 16;
  return __builtin_bit_cast(float, u);
}
__device__ __forceinline__ bf16x8 bfz() {
  bf16x8 v;
#pragma unroll
  for (int j = 0; j < 8; j++) v[j] = (__bf16)0.0f;
  return v;
}

// ---------------------------------------------------------------------------
// NCHW f32 -> NHWC bf16 tokens (N,4096,256), via LDS transpose.
// ---------------------------------------------------------------------------
__global__ __launch_bounds__(256) void nchw_to_tok(const float* __restrict__ x,
                                                   unsigned short* __restrict__ xt) {
  __shared__ float lds[64][65];
  const int p0 = blockIdx.x * 64, c0 = blockIdx.y * 64, n = blockIdx.z;
  const int t = threadIdx.x;
  const int pp = t & 63, ccb = t >> 6;
  const float* xb = x + ((size_t)n * 256 + c0) * 4096 + p0;
#pragma unroll
  for (int i = 0; i < 16; i++) {
    int cc = ccb * 16 + i;
    lds[pp][cc] = xb[(size_t)cc * 4096 + pp];
  }
  __syncthreads();
#pragma unroll
  for (int i = 0; i < 2; i++) {
    int pp2 = (t >> 3) + i * 32;
    int c8 = (t & 7) * 8;
    us8 v;
#pragma unroll
    for (int j = 0; j < 8; j++) v[j] = f2bf(lds[pp2][c8 + j]);
    *(us8*)&xt[((size_t)(n * 4096 + p0 + pp2)) * 256 + c0 + c8] = v;
  }
}

// ---------------------------------------------------------------------------
// out = x + y2 + d  (tokens bf16 -> NCHW f32), via LDS transpose.
// ---------------------------------------------------------------------------
__global__ __launch_bounds__(256) void fuse_out_k(
    const float* __restrict__ x, const unsigned short* __restrict__ y2t,
    const unsigned short* __restrict__ dt, float* __restrict__ out) {
  __shared__ float lds[64][65];
  const int p0 = blockIdx.x * 64, c0 = blockIdx.y * 64, n = blockIdx.z;
  const int t = threadIdx.x;
#pragma unroll
  for (int i = 0; i < 2; i++) {
    int pp = (t >> 3) + i * 32;
    int c8 = (t & 7) * 8;
    size_t base = ((size_t)(n * 4096 + p0 + pp)) * 256 + c0 + c8;
    us8 a = *(const us8*)&y2t[base];
    us8 b = *(const us8*)&dt[base];
#pragma unroll
    for (int j = 0; j < 8; j++) lds[pp][c8 + j] = bf2f(a[j]) + bf2f(b[j]);
  }
  __syncthreads();
  const int pp2 = t & 63, ccb = t >> 6;
  const size_t nco = ((size_t)n * 256 + c0) * 4096 + p0;
#pragma unroll
  for (int i = 0; i < 16; i++) {
    int cc = ccb * 16 + i;
    size_t idx = nco + (size_t)cc * 4096 + pp2;
    out[idx] = x[idx] + lds[pp2][cc];
  }
}

// ---------------------------------------------------------------------------
// Weight conversions (batched into 2 launches).
// conv: (Co,Ci,3,3) f32 -> (Co, 9*Ci) bf16 with k = tap*Ci + ci
// ---------------------------------------------------------------------------
__global__ void cvt_conv_both(const float* __restrict__ w1, unsigned short* __restrict__ o1,
                              const float* __restrict__ w2, unsigned short* __restrict__ o2) {
  int idx = blockIdx.x * 256 + threadIdx.x;
  const float* w;
  unsigned short* o;
  int Ci;
  if (idx < 294912) { w = w1; o = o1; Ci = 256; }
  else {
    idx -= 294912;
    if (idx >= 294912) return;
    w = w2; o = o2; Ci = 128;
  }
  int ci = idx % Ci;
  int r = idx / Ci;
  int tap = r % 9;
  int co = r / 9;
  o[idx] = f2bf(w[((size_t)co * Ci + ci) * 9 + tap]);
}

__global__ void cvt_plain_all(
    const float* __restrict__ a0, unsigned short* __restrict__ b0,
    const float* __restrict__ a1, unsigned short* __restrict__ b1,
    const float* __restrict__ a2, unsigned short* __restrict__ b2,
    const float* __restrict__ a3, unsigned short* __restrict__ b3,
    const float* __restrict__ a4, unsigned short* __restrict__ b4) {
  int idx = blockIdx.x * 256 + threadIdx.x;
  const float* s;
  unsigned short* d;
  int off;
  if (idx < 65536)       { s = a0; d = b0; off = idx; }
  else if (idx < 120832) { s = a1; d = b1; off = idx - 65536; }
  else if (idx < 186368) { s = a2; d = b2; off = idx - 120832; }
  else if (idx < 382976) { s = a3; d = b3; off = idx - 186368; }
  else if (idx < 579584) { s = a4; d = b4; off = idx - 382976; }
  else return;
  d[off] = f2bf(s[off]);
}

// ---------------------------------------------------------------------------
// Unified bf16 MFMA GEMM, 64x64 tile, 4 waves (each 32x32 out), BK=64,
// reg-staged prefetch of tile k+1 overlapping the MFMA cluster.
//   A: tokens (16384, K) bf16; CONV (CIN>0): K = 9*CIN, implicit im2col.
//   B: (Co, K) bf16 row-major.
// LDS fragment-major: chunk id = ((sub*2+ks)*64 + kg*16 + idx16); both the
// stage write and the frag read are lane-linear 1024B sweeps (conflict-free).
// EPI: 0 = bias->bf16 | 1 = bias->f32 | 2 = BN+SiLU->bf16 (no bias)
//      3 = bias+BN->bf16 | 4 = bias+SiLU->bf16
// ---------------------------------------------------------------------------
template <int EPI, int CIN>
__global__ __launch_bounds__(256) void mfma_gemm(
    const unsigned short* __restrict__ A, const unsigned short* __restrict__ Bw,
    const float* __restrict__ bias, int K, int Co, void* __restrict__ outv,
    const float* __restrict__ e0, const float* __restrict__ e1,
    const float* __restrict__ e2, const float* __restrict__ e3) {
  __shared__ bf16x8 Asm[512];  // 8 KB
  __shared__ bf16x8 Bsm[512];  // 8 KB
  const int t = threadIdx.x;
  const int lane = t & 63;
  const int wv = t >> 6;
  const int wr = wv >> 1, wc = wv & 1;
  const int rb = blockIdx.y * 64, cb = blockIdx.x * 64;

  f32x4 acc[2][2];
#pragma unroll
  for (int i = 0; i < 2; i++)
#pragma unroll
    for (int j = 0; j < 2; j++) acc[i][j] = (f32x4){0.f, 0.f, 0.f, 0.f};

  auto loadA = [&](int c, int kb) -> bf16x8 {
    int row16 = c & 15, kg = (c >> 4) & 3, ks = (c >> 6) & 1, msub = c >> 7;
    int row = msub * 16 + row16;
    int koff = ks * 32 + kg * 8;
    if constexpr (CIN > 0) {
      int tap = kb / CIN, ci = kb % CIN + koff;
      int dy = tap / 3 - 1, dx = tap % 3 - 1;
      int grow = rb + row;
      int n = grow >> 12, p = grow & 4095;
      int h = (p >> 6) + dy, w = (p & 63) + dx;
      if (((unsigned)h < 64u) && ((unsigned)w < 64u))
        return *(const bf16x8*)&A[((size_t)(n * 4096 + h * 64 + w)) * CIN + ci];
      return bfz();
    } else {
      return *(const bf16x8*)&A[(size_t)(rb + row) * K + kb + koff];
    }
  };
  auto loadB = [&](int c, int kb) -> bf16x8 {
    int col16 = c & 15, kg = (c >> 4) & 3, ks = (c >> 6) & 1, csub = c >> 7;
    int col = cb + csub * 16 + col16;
    int koff = ks * 32 + kg * 8;
    if (col < Co) return *(const bf16x8*)&Bw[(size_t)col * K + kb + koff];
    return bfz();
  };

  bf16x8 ra0 = loadA(t, 0), ra1 = loadA(t + 256, 0);
  bf16x8 rb0 = loadB(t, 0), rb1 = loadB(t + 256, 0);

  for (int kb = 0; kb < K; kb += 64) {
    Asm[t] = ra0; Asm[t + 256] = ra1;
    Bsm[t] = rb0; Bsm[t + 256] = rb1;
    __syncthreads();
    if (kb + 64 < K) {
      ra0 = loadA(t, kb + 64);
      ra1 = loadA(t + 256, kb + 64);
      rb0 = loadB(t, kb + 64);
      rb1 = loadB(t + 256, kb + 64);
    }
#pragma unroll
    for (int ks = 0; ks < 2; ks++) {
      bf16x8 af[2], bfr[2];
#pragma unroll
      for (int mi = 0; mi < 2; mi++) af[mi] = Asm[((wr * 2 + mi) * 2 + ks) * 64 + lane];
#pragma unroll
      for (int ni = 0; ni < 2; ni++) bfr[ni] = Bsm[((wc * 2 + ni) * 2 + ks) * 64 + lane];
#pragma unroll
      for (int mi = 0; mi < 2; mi++)
#pragma unroll
        for (int ni = 0; ni < 2; ni++)
          acc[mi][ni] = __builtin_amdgcn_mfma_f32_16x16x32_bf16(af[mi], bfr[ni],
                                                                acc[mi][ni], 0, 0, 0);
    }
    __syncthreads();
  }

  // ---- epilogue.  C/D: col = lane&15, row = (lane>>4)*4 + reg
  const int lr = lane & 15, kg4 = (lane >> 4) * 4;
#pragma unroll
  for (int mi = 0; mi < 2; mi++) {
#pragma unroll
    for (int ni = 0; ni < 2; ni++) {
      int gcol = cb + wc * 32 + ni * 16 + lr;
      if (gcol < Co) {
        float bval = (EPI == 2) ? 0.f : bias[gcol];
        float s = 1.f, tt = 0.f;
        if (EPI == 2 || EPI == 3) {
          s = e0[gcol] * rsqrtf(e3[gcol] + EPSV);
          tt = e1[gcol] - e2[gcol] * s;
        }
#pragma unroll
        for (int j = 0; j < 4; j++) {
          int grow = rb + wr * 32 + mi * 16 + kg4 + j;
          float v = acc[mi][ni][j] + bval;
          if (EPI == 2) v = silu_f(v * s + tt);
          if (EPI == 3) v = v * s + tt;
          if (EPI == 4) v = silu_f(v);
          if (EPI == 1)
            ((float*)outv)[(size_t)grow * Co + gcol] = v;
          else
            ((unsigned short*)outv)[(size_t)grow * Co + gcol] = f2bf(v);
        }
      }
    }
  }
}

// ---------------------------------------------------------------------------
// DCNv4 core.  value: bf16 tokens (N,4096,256), om: f32 tokens (N,4096,216).
// ---------------------------------------------------------------------------
__global__ __launch_bounds__(256) void dcn_core(
    const unsigned short* __restrict__ value, const float* __restrict__ om,
    unsigned short* __restrict__ out) {
  const int p = blockIdx.x;
  const int n = blockIdx.y;
  const int c = threadIdx.x & 31;
  const int g = threadIdx.x >> 5;
  const int h0 = p >> 6, w0 = p & 63;
  const float* omp = om + ((size_t)(n * 4096 + p)) * 216 + g * 27;
  const unsigned short* vb = value + ((size_t)(n * 4096)) * 256 + g * 32 + c;
  float acc = 0.f;
#pragma unroll
  for (int k = 0; k < 9; k++) {
    float ox = omp[2 * k], oy = omp[2 * k + 1], mk = omp[18 + k];
    float px = (float)(w0 + (k % 3) - 1) + ox;
    float py = (float)(h0 + (k / 3) - 1) + oy;
    float x0f = floorf(px), y0f = floorf(py);
    float lx = px - x0f, ly = py - y0f;
    int x0 = (int)x0f, y0 = (int)y0f;
    int x1 = x0 + 1, y1 = y0 + 1;
    float w00 = (1.f - ly) * (1.f - lx), w01 = (1.f - ly) * lx;
    float w10 = ly * (1.f - lx), w11 = ly * lx;
    bool vx0 = (x0 >= 0) & (x0 < 64), vx1 = (x1 >= 0) & (x1 < 64);
    bool vy0 = (y0 >= 0) & (y0 < 64), vy1 = (y1 >= 0) & (y1 < 64);
    int cx0 = min(max(x0, 0), 63), cx1 = min(max(x1, 0), 63);
    int cy0 = min(max(y0, 0), 63), cy1 = min(max(y1, 0), 63);
    float v00 = bf2f(vb[(size_t)(cy0 * 64 + cx0) * 256]);
    float v01 = bf2f(vb[(size_t)(cy0 * 64 + cx1) * 256]);
    float v10 = bf2f(vb[(size_t)(cy1 * 64 + cx0) * 256]);
    float v11 = bf2f(vb[(size_t)(cy1 * 64 + cx1) * 256]);
    float sm = v00 * (w00 * (vy0 && vx0)) + v01 * (w01 * (vy0 && vx1)) +
               v10 * (w10 * (vy1 && vx0)) + v11 * (w11 * (vy1 && vx1));
    acc += mk * sm;
  }
  out[((size_t)(n * 4096 + p)) * 256 + g * 32 + c] = f2bf(acc);
}

// ---------------------------------------------------------------------------
extern "C" void kernel_launch(void* const* d_in, const int* in_sizes, int n_in,
                              void* d_out, int out_size, void* d_ws,
                              size_t ws_size, hipStream_t stream) {
  const float* x      = (const float*)d_in[0];
  const float* cv1_w  = (const float*)d_in[1];
  const float* cv1_g  = (const float*)d_in[2];
  const float* cv1_b  = (const float*)d_in[3];
  const float* cv1_m  = (const float*)d_in[4];
  const float* cv1_v  = (const float*)d_in[5];
  const float* cv2_w  = (const float*)d_in[6];
  const float* cv2_g  = (const float*)d_in[7];
  const float* cv2_b  = (const float*)d_in[8];
  const float* cv2_m  = (const float*)d_in[9];
  const float* cv2_v  = (const float*)d_in[10];
  const float* val_w  = (const float*)d_in[11];
  const float* val_b  = (const float*)d_in[12];
  const float* om_w   = (const float*)d_in[13];
  const float* om_b   = (const float*)d_in[14];
  const float* outp_w = (const float*)d_in[15];
  const float* outp_b = (const float*)d_in[16];
  const float* bn3_g  = (const float*)d_in[17];
  const float* bn3_b  = (const float*)d_in[18];
  const float* bn3_m  = (const float*)d_in[19];
  const float* bn3_v  = (const float*)d_in[20];
  const float* pw1_w  = (const float*)d_in[21];
  const float* pw1_b  = (const float*)d_in[22];
  const float* pw2_w  = (const float*)d_in[23];
  const float* pw2_b  = (const float*)d_in[24];
  float* out = (float*)d_out;

  char* w = (char*)d_ws;
  auto alloc = [&](size_t bytes) {
    char* p = w;
    w += (bytes + 255) & ~(size_t)255;
    return p;
  };
  unsigned short* xt    = (unsigned short*)alloc(16384ull * 256 * 2);
  unsigned short* y1t   = (unsigned short*)alloc(16384ull * 128 * 2);
  unsigned short* y2t   = (unsigned short*)alloc(16384ull * 256 * 2);
  unsigned short* valt  = (unsigned short*)alloc(16384ull * 256 * 2);
  float*          omf   = (float*)alloc(16384ull * 216 * 4);
  unsigned short* dcnt  = (unsigned short*)alloc(16384ull * 256 * 2);
  unsigned short* d1t   = (unsigned short*)alloc(16384ull * 256 * 2);
  unsigned short* p1t   = (unsigned short*)alloc(16384ull * 768 * 2);
  unsigned short* dt    = (unsigned short*)alloc(16384ull * 256 * 2);
  unsigned short* wc1   = (unsigned short*)alloc(128ull * 2304 * 2);
  unsigned short* wc2   = (unsigned short*)alloc(256ull * 1152 * 2);
  unsigned short* wval  = (unsigned short*)alloc(256ull * 256 * 2);
  unsigned short* wom   = (unsigned short*)alloc(216ull * 256 * 2);
  unsigned short* woutp = (unsigned short*)alloc(256ull * 256 * 2);
  unsigned short* wpw1  = (unsigned short*)alloc(768ull * 256 * 2);
  unsigned short* wpw2  = (unsigned short*)alloc(256ull * 768 * 2);

  // conversions (3 launches)
  nchw_to_tok<<<dim3(64, 4, 4), 256, 0, stream>>>(x, xt);
  cvt_conv_both<<<2304, 256, 0, stream>>>(cv1_w, wc1, cv2_w, wc2);
  cvt_plain_all<<<2265, 256, 0, stream>>>(val_w, wval, om_w, wom, outp_w, woutp,
                                          pw1_w, wpw1, pw2_w, wpw2);

  // y path (convs as implicit GEMM)
  mfma_gemm<2, 256><<<dim3(2, 256), 256, 0, stream>>>(
      xt, wc1, nullptr, 2304, 128, y1t, cv1_g, cv1_b, cv1_m, cv1_v);
  mfma_gemm<2, 128><<<dim3(4, 256), 256, 0, stream>>>(
      y1t, wc2, nullptr, 1152, 256, y2t, cv2_g, cv2_b, cv2_m, cv2_v);

  // dcn path
  mfma_gemm<0, 0><<<dim3(4, 256), 256, 0, stream>>>(
      xt, wval, val_b, 256, 256, valt, nullptr, nullptr, nullptr, nullptr);
  mfma_gemm<1, 0><<<dim3(4, 256), 256, 0, stream>>>(
      xt, wom, om_b, 256, 216, omf, nullptr, nullptr, nullptr, nullptr);
  dcn_core<<<dim3(4096, 4), 256, 0, stream>>>(valt, omf, dcnt);
  mfma_gemm<3, 0><<<dim3(4, 256), 256, 0, stream>>>(
      dcnt, woutp, outp_b, 256, 256, d1t, bn3_g, bn3_b, bn3_m, bn3_v);
  mfma_gemm<4, 0><<<dim3(12, 256), 256, 0, stream>>>(
      d1t, wpw1, pw1_b, 256, 768, p1t, nullptr, nullptr, nullptr, nullptr);
  mfma_gemm<0, 0><<<dim3(4, 256), 256, 0, stream>>>(
      p1t, wpw2, pw2_b, 768, 256, dt, nullptr, nullptr, nullptr, nullptr);

  // out = x + y2 + d
  fuse_out_k<<<dim3(64, 4, 4), 256, 0, stream>>>(x, y2t, dt, out);
}

// Round 4
// 211.989 us; speedup vs baseline: 13.4809x; 1.1640x over previous
//
#include <hip/hip_runtime.h>
#include <math.h>

typedef __attribute__((ext_vector_type(8))) __bf16 bf16x8;
typedef __attribute__((ext_vector_type(8))) unsigned short us8;
typedef __attribute__((ext_vector_type(4))) unsigned short us4;
typedef __attribute__((ext_vector_type(4))) float f32x4;
typedef __attribute__((ext_vector_type(4))) int i32x4;
typedef unsigned int uint32;

#define EPSV 1e-5f

__device__ __forceinline__ float silu_f(float v) { return v / (1.f + __expf(-v)); }

__device__ __forceinline__ unsigned short f2bf(float f) {
  uint32 u = __builtin_bit_cast(uint32, f);
  u += 0x7fffu + ((u >> 16) & 1u);   // RNE
  return (unsigned short)(u >> 16);
}
__device__ __forceinline__ float bf2f(unsigned short h) {
  uint32 u = ((uint32)h) << 16;
  return __builtin_bit_cast(float, u);
}
__device__ __forceinline__ bf16x8 bfz() {
  bf16x8 v;
#pragma unroll
  for (int j = 0; j < 8; j++) v[j] = (__bf16)0.0f;
  return v;
}

// ---------------------------------------------------------------------------
// NCHW f32 -> NHWC bf16 tokens (N,4096,256), via LDS transpose.
// ---------------------------------------------------------------------------
__global__ __launch_bounds__(256) void nchw_to_tok(const float* __restrict__ x,
                                                   unsigned short* __restrict__ xt) {
  __shared__ float lds[64][65];
  const int p0 = blockIdx.x * 64, c0 = blockIdx.y * 64, n = blockIdx.z;
  const int t = threadIdx.x;
  const int pp = t & 63, ccb = t >> 6;
  const float* xb = x + ((size_t)n * 256 + c0) * 4096 + p0;
#pragma unroll
  for (int i = 0; i < 16; i++) {
    int cc = ccb * 16 + i;
    lds[pp][cc] = xb[(size_t)cc * 4096 + pp];
  }
  __syncthreads();
#pragma unroll
  for (int i = 0; i < 2; i++) {
    int pp2 = (t >> 3) + i * 32;
    int c8 = (t & 7) * 8;
    us8 v;
#pragma unroll
    for (int j = 0; j < 8; j++) v[j] = f2bf(lds[pp2][c8 + j]);
    *(us8*)&xt[((size_t)(n * 4096 + p0 + pp2)) * 256 + c0 + c8] = v;
  }
}

// ---------------------------------------------------------------------------
// out = x + y2 + d  (tokens bf16 -> NCHW f32), via LDS transpose.
// ---------------------------------------------------------------------------
__global__ __launch_bounds__(256) void fuse_out_k(
    const float* __restrict__ x, const unsigned short* __restrict__ y2t,
    const unsigned short* __restrict__ dt, float* __restrict__ out) {
  __shared__ float lds[64][65];
  const int p0 = blockIdx.x * 64, c0 = blockIdx.y * 64, n = blockIdx.z;
  const int t = threadIdx.x;
#pragma unroll
  for (int i = 0; i < 2; i++) {
    int pp = (t >> 3) + i * 32;
    int c8 = (t & 7) * 8;
    size_t base = ((size_t)(n * 4096 + p0 + pp)) * 256 + c0 + c8;
    us8 a = *(const us8*)&y2t[base];
    us8 b = *(const us8*)&dt[base];
#pragma unroll
    for (int j = 0; j < 8; j++) lds[pp][c8 + j] = bf2f(a[j]) + bf2f(b[j]);
  }
  __syncthreads();
  const int pp2 = t & 63, ccb = t >> 6;
  const size_t nco = ((size_t)n * 256 + c0) * 4096 + p0;
#pragma unroll
  for (int i = 0; i < 16; i++) {
    int cc = ccb * 16 + i;
    size_t idx = nco + (size_t)cc * 4096 + pp2;
    out[idx] = x[idx] + lds[pp2][cc];
  }
}

// ---------------------------------------------------------------------------
// All weight conversions in ONE launch.
// conv weights: (Co,Ci,3,3) f32 -> (Co, 9*Ci) bf16 with k = tap*Ci + ci
// ---------------------------------------------------------------------------
__global__ void cvt_all(
    const float* __restrict__ c1, unsigned short* __restrict__ o1,
    const float* __restrict__ c2, unsigned short* __restrict__ o2,
    const float* __restrict__ a0, unsigned short* __restrict__ b0,
    const float* __restrict__ a1, unsigned short* __restrict__ b1,
    const float* __restrict__ a2, unsigned short* __restrict__ b2,
    const float* __restrict__ a3, unsigned short* __restrict__ b3,
    const float* __restrict__ a4, unsigned short* __restrict__ b4) {
  int idx = blockIdx.x * 256 + threadIdx.x;
  if (idx < 294912) {
    int ci = idx & 255, r = idx >> 8;
    int tap = r % 9, co = r / 9;
    o1[idx] = f2bf(c1[((size_t)co * 256 + ci) * 9 + tap]);
    return;
  }
  idx -= 294912;
  if (idx < 294912) {
    int ci = idx & 127, r = idx >> 7;
    int tap = r % 9, co = r / 9;
    o2[idx] = f2bf(c2[((size_t)co * 128 + ci) * 9 + tap]);
    return;
  }
  idx -= 294912;
  const float* s;
  unsigned short* d;
  int off;
  if (idx < 65536)       { s = a0; d = b0; off = idx; }
  else if (idx < 120832) { s = a1; d = b1; off = idx - 65536; }
  else if (idx < 186368) { s = a2; d = b2; off = idx - 120832; }
  else if (idx < 382976) { s = a3; d = b3; off = idx - 186368; }
  else if (idx < 579584) { s = a4; d = b4; off = idx - 382976; }
  else return;
  d[off] = f2bf(s[off]);
}

// ---------------------------------------------------------------------------
// Unified bf16 MFMA GEMM, 64x64 tile, 4 waves (each 32x32 out), BK=64,
// reg-staged prefetch of tile k+1 overlapping the MFMA cluster.
//   A: tokens (16384, K) bf16; CONV (CIN>0): K = 9*CIN, implicit im2col.
//   B: (Co, K) bf16 row-major.
// LDS fragment-major: chunk id = ((sub*2+ks)*64 + kg*16 + idx16); both the
// stage write and the frag read are lane-linear 1024B sweeps (conflict-free).
// EPI: 0 = bias->bf16 | 1 = bias->f32 | 2 = BN+SiLU->bf16 (no bias)
//      3 = bias+BN->bf16 | 4 = bias+SiLU->bf16
//      5 = split val/om: col<256 -> bf16 outv (stride 256, bias=bias);
//          col>=256  -> f32 (float*)e1 (stride 216, bias=e0[col-256])
// ---------------------------------------------------------------------------
template <int EPI, int CIN>
__global__ __launch_bounds__(256) void mfma_gemm(
    const unsigned short* __restrict__ A, const unsigned short* __restrict__ Bw,
    const float* __restrict__ bias, int K, int Co, void* __restrict__ outv,
    const float* __restrict__ e0, const float* __restrict__ e1,
    const float* __restrict__ e2, const float* __restrict__ e3) {
  __shared__ bf16x8 Asm[512];  // 8 KB
  __shared__ bf16x8 Bsm[512];  // 8 KB
  const int t = threadIdx.x;
  const int lane = t & 63;
  const int wv = t >> 6;
  const int wr = wv >> 1, wc = wv & 1;
  const int rb = blockIdx.y * 64, cb = blockIdx.x * 64;

  f32x4 acc[2][2];
#pragma unroll
  for (int i = 0; i < 2; i++)
#pragma unroll
    for (int j = 0; j < 2; j++) acc[i][j] = (f32x4){0.f, 0.f, 0.f, 0.f};

  auto loadA = [&](int c, int kb) -> bf16x8 {
    int row16 = c & 15, kg = (c >> 4) & 3, ks = (c >> 6) & 1, msub = c >> 7;
    int row = msub * 16 + row16;
    int koff = ks * 32 + kg * 8;
    if constexpr (CIN > 0) {
      int tap = kb / CIN, ci = kb % CIN + koff;
      int dy = tap / 3 - 1, dx = tap % 3 - 1;
      int grow = rb + row;
      int n = grow >> 12, p = grow & 4095;
      int h = (p >> 6) + dy, w = (p & 63) + dx;
      if (((unsigned)h < 64u) && ((unsigned)w < 64u))
        return *(const bf16x8*)&A[((size_t)(n * 4096 + h * 64 + w)) * CIN + ci];
      return bfz();
    } else {
      return *(const bf16x8*)&A[(size_t)(rb + row) * K + kb + koff];
    }
  };
  auto loadB = [&](int c, int kb) -> bf16x8 {
    int col16 = c & 15, kg = (c >> 4) & 3, ks = (c >> 6) & 1, csub = c >> 7;
    int col = cb + csub * 16 + col16;
    int koff = ks * 32 + kg * 8;
    if (col < Co) return *(const bf16x8*)&Bw[(size_t)col * K + kb + koff];
    return bfz();
  };

  bf16x8 ra0 = loadA(t, 0), ra1 = loadA(t + 256, 0);
  bf16x8 rb0 = loadB(t, 0), rb1 = loadB(t + 256, 0);

  for (int kb = 0; kb < K; kb += 64) {
    Asm[t] = ra0; Asm[t + 256] = ra1;
    Bsm[t] = rb0; Bsm[t + 256] = rb1;
    __syncthreads();
    if (kb + 64 < K) {
      ra0 = loadA(t, kb + 64);
      ra1 = loadA(t + 256, kb + 64);
      rb0 = loadB(t, kb + 64);
      rb1 = loadB(t + 256, kb + 64);
    }
#pragma unroll
    for (int ks = 0; ks < 2; ks++) {
      bf16x8 af[2], bfr[2];
#pragma unroll
      for (int mi = 0; mi < 2; mi++) af[mi] = Asm[((wr * 2 + mi) * 2 + ks) * 64 + lane];
#pragma unroll
      for (int ni = 0; ni < 2; ni++) bfr[ni] = Bsm[((wc * 2 + ni) * 2 + ks) * 64 + lane];
#pragma unroll
      for (int mi = 0; mi < 2; mi++)
#pragma unroll
        for (int ni = 0; ni < 2; ni++)
          acc[mi][ni] = __builtin_amdgcn_mfma_f32_16x16x32_bf16(af[mi], bfr[ni],
                                                                acc[mi][ni], 0, 0, 0);
    }
    __syncthreads();
  }

  // ---- epilogue.  C/D: col = lane&15, row = (lane>>4)*4 + reg
  const int lr = lane & 15, kg4 = (lane >> 4) * 4;
#pragma unroll
  for (int mi = 0; mi < 2; mi++) {
#pragma unroll
    for (int ni = 0; ni < 2; ni++) {
      int gcol = cb + wc * 32 + ni * 16 + lr;
      if (gcol >= Co) continue;
      float bval, s = 1.f, tt = 0.f;
      if (EPI == 2) bval = 0.f;
      else if (EPI == 5) bval = (gcol < 256) ? bias[gcol] : e0[gcol - 256];
      else bval = bias[gcol];
      if (EPI == 2 || EPI == 3) {
        s = e0[gcol] * rsqrtf(e3[gcol] + EPSV);
        tt = e1[gcol] - e2[gcol] * s;
      }
#pragma unroll
      for (int j = 0; j < 4; j++) {
        int grow = rb + wr * 32 + mi * 16 + kg4 + j;
        float v = acc[mi][ni][j] + bval;
        if (EPI == 2) v = silu_f(v * s + tt);
        if (EPI == 3) v = v * s + tt;
        if (EPI == 4) v = silu_f(v);
        if (EPI == 1) {
          ((float*)outv)[(size_t)grow * Co + gcol] = v;
        } else if (EPI == 5) {
          if (gcol < 256)
            ((unsigned short*)outv)[(size_t)grow * 256 + gcol] = f2bf(v);
          else
            ((float*)e1)[(size_t)grow * 216 + (gcol - 256)] = v;
        } else {
          ((unsigned short*)outv)[(size_t)grow * Co + gcol] = f2bf(v);
        }
      }
    }
  }
}

// ---------------------------------------------------------------------------
// DCNv4 core v2 (two-phase).  value: bf16 tokens (N,4096,256),
// om: f32 tokens (N,4096,216), out: bf16 tokens.
// Block = 256 threads = 4 pixels.  Phase 1: 288 taps (pix,g,k) computed once
// into LDS (weights premultiplied by mask*valid; clamped addresses).
// Phase 2: 8 lanes/group x 4 channels each (us4 loads).
// ---------------------------------------------------------------------------
__global__ __launch_bounds__(256) void dcn_core2(
    const unsigned short* __restrict__ value, const float* __restrict__ om,
    unsigned short* __restrict__ out) {
  __shared__ f32x4 wgt[288];
  __shared__ i32x4 adr[288];
  const int n = blockIdx.y;
  const int p0 = blockIdx.x * 4;
  const int t = threadIdx.x;

  for (int idx = t; idx < 288; idx += 256) {
    int pi = idx / 72;
    int gk = idx - pi * 72;
    int g = gk / 9, k = gk - g * 9;
    int p = p0 + pi;
    int h0 = p >> 6, w0 = p & 63;
    const float* omp = om + ((size_t)(n * 4096 + p)) * 216 + g * 27;
    float ox = omp[2 * k], oy = omp[2 * k + 1], mk = omp[18 + k];
    float px = (float)(w0 + (k % 3) - 1) + ox;
    float py = (float)(h0 + (k / 3) - 1) + oy;
    float x0f = floorf(px), y0f = floorf(py);
    float lx = px - x0f, ly = py - y0f;
    int x0 = (int)x0f, y0 = (int)y0f;
    int x1 = x0 + 1, y1 = y0 + 1;
    bool vx0 = (unsigned)x0 < 64u, vx1 = (unsigned)x1 < 64u;
    bool vy0 = (unsigned)y0 < 64u, vy1 = (unsigned)y1 < 64u;
    int cx0 = min(max(x0, 0), 63), cx1 = min(max(x1, 0), 63);
    int cy0 = min(max(y0, 0), 63), cy1 = min(max(y1, 0), 63);
    f32x4 w4;
    w4[0] = (1.f - ly) * (1.f - lx) * mk * (float)(vy0 && vx0);
    w4[1] = (1.f - ly) * lx * mk * (float)(vy0 && vx1);
    w4[2] = ly * (1.f - lx) * mk * (float)(vy1 && vx0);
    w4[3] = ly * lx * mk * (float)(vy1 && vx1);
    i32x4 a4;
    a4[0] = (cy0 * 64 + cx0) * 256;
    a4[1] = (cy0 * 64 + cx1) * 256;
    a4[2] = (cy1 * 64 + cx0) * 256;
    a4[3] = (cy1 * 64 + cx1) * 256;
    wgt[idx] = w4;
    adr[idx] = a4;
  }
  __syncthreads();

  const int pi = t >> 6;
  const int g = (t >> 3) & 7;
  const int l = t & 7;
  const int p = p0 + pi;
  const unsigned short* vb = value + ((size_t)n * 4096) * 256 + g * 32 + l * 4;
  const int bix = (pi * 8 + g) * 9;
  float a0 = 0.f, a1 = 0.f, a2 = 0.f, a3 = 0.f;
#pragma unroll
  for (int k = 0; k < 9; k++) {
    f32x4 wv = wgt[bix + k];
    i32x4 av = adr[bix + k];
    us4 q0 = *(const us4*)(vb + av[0]);
    us4 q1 = *(const us4*)(vb + av[1]);
    us4 q2 = *(const us4*)(vb + av[2]);
    us4 q3 = *(const us4*)(vb + av[3]);
    a0 += wv[0] * bf2f(q0[0]) + wv[1] * bf2f(q1[0]) + wv[2] * bf2f(q2[0]) + wv[3] * bf2f(q3[0]);
    a1 += wv[0] * bf2f(q0[1]) + wv[1] * bf2f(q1[1]) + wv[2] * bf2f(q2[1]) + wv[3] * bf2f(q3[1]);
    a2 += wv[0] * bf2f(q0[2]) + wv[1] * bf2f(q1[2]) + wv[2] * bf2f(q2[2]) + wv[3] * bf2f(q3[2]);
    a3 += wv[0] * bf2f(q0[3]) + wv[1] * bf2f(q1[3]) + wv[2] * bf2f(q2[3]) + wv[3] * bf2f(q3[3]);
  }
  us4 o;
  o[0] = f2bf(a0); o[1] = f2bf(a1); o[2] = f2bf(a2); o[3] = f2bf(a3);
  *(us4*)&out[((size_t)(n * 4096 + p)) * 256 + g * 32 + l * 4] = o;
}

// ---------------------------------------------------------------------------
extern "C" void kernel_launch(void* const* d_in, const int* in_sizes, int n_in,
                              void* d_out, int out_size, void* d_ws,
                              size_t ws_size, hipStream_t stream) {
  const float* x      = (const float*)d_in[0];
  const float* cv1_w  = (const float*)d_in[1];
  const float* cv1_g  = (const float*)d_in[2];
  const float* cv1_b  = (const float*)d_in[3];
  const float* cv1_m  = (const float*)d_in[4];
  const float* cv1_v  = (const float*)d_in[5];
  const float* cv2_w  = (const float*)d_in[6];
  const float* cv2_g  = (const float*)d_in[7];
  const float* cv2_b  = (const float*)d_in[8];
  const float* cv2_m  = (const float*)d_in[9];
  const float* cv2_v  = (const float*)d_in[10];
  const float* val_w  = (const float*)d_in[11];
  const float* val_b  = (const float*)d_in[12];
  const float* om_w   = (const float*)d_in[13];
  const float* om_b   = (const float*)d_in[14];
  const float* outp_w = (const float*)d_in[15];
  const float* outp_b = (const float*)d_in[16];
  const float* bn3_g  = (const float*)d_in[17];
  const float* bn3_b  = (const float*)d_in[18];
  const float* bn3_m  = (const float*)d_in[19];
  const float* bn3_v  = (const float*)d_in[20];
  const float* pw1_w  = (const float*)d_in[21];
  const float* pw1_b  = (const float*)d_in[22];
  const float* pw2_w  = (const float*)d_in[23];
  const float* pw2_b  = (const float*)d_in[24];
  float* out = (float*)d_out;

  char* w = (char*)d_ws;
  auto alloc = [&](size_t bytes) {
    char* p = w;
    w += (bytes + 255) & ~(size_t)255;
    return p;
  };
  unsigned short* xt    = (unsigned short*)alloc(16384ull * 256 * 2);
  unsigned short* y1t   = (unsigned short*)alloc(16384ull * 128 * 2);
  unsigned short* y2t   = (unsigned short*)alloc(16384ull * 256 * 2);
  unsigned short* valt  = (unsigned short*)alloc(16384ull * 256 * 2);
  float*          omf   = (float*)alloc(16384ull * 216 * 4);
  unsigned short* dcnt  = (unsigned short*)alloc(16384ull * 256 * 2);
  unsigned short* d1t   = (unsigned short*)alloc(16384ull * 256 * 2);
  unsigned short* p1t   = (unsigned short*)alloc(16384ull * 768 * 2);
  unsigned short* dt    = (unsigned short*)alloc(16384ull * 256 * 2);
  unsigned short* wc1   = (unsigned short*)alloc(128ull * 2304 * 2);
  unsigned short* wc2   = (unsigned short*)alloc(256ull * 1152 * 2);
  // wval and wom MUST be contiguous (fused val/om GEMM B-matrix, 472 x 256):
  unsigned short* wval  = (unsigned short*)alloc(256ull * 256 * 2);   // 131072 B (256-mult)
  unsigned short* wom   = (unsigned short*)alloc(216ull * 256 * 2);   // = wval + 65536 elems
  unsigned short* woutp = (unsigned short*)alloc(256ull * 256 * 2);
  unsigned short* wpw1  = (unsigned short*)alloc(768ull * 256 * 2);
  unsigned short* wpw2  = (unsigned short*)alloc(256ull * 768 * 2);

  // conversions (2 launches)
  nchw_to_tok<<<dim3(64, 4, 4), 256, 0, stream>>>(x, xt);
  cvt_all<<<4568, 256, 0, stream>>>(cv1_w, wc1, cv2_w, wc2, val_w, wval, om_w, wom,
                                    outp_w, woutp, pw1_w, wpw1, pw2_w, wpw2);

  // y path (convs as implicit GEMM)
  mfma_gemm<2, 256><<<dim3(2, 256), 256, 0, stream>>>(
      xt, wc1, nullptr, 2304, 128, y1t, cv1_g, cv1_b, cv1_m, cv1_v);
  mfma_gemm<2, 128><<<dim3(4, 256), 256, 0, stream>>>(
      y1t, wc2, nullptr, 1152, 256, y2t, cv2_g, cv2_b, cv2_m, cv2_v);

  // dcn path: fused val+om projection (B rows 0-255 = val_w, 256-471 = om_w)
  mfma_gemm<5, 0><<<dim3(8, 256), 256, 0, stream>>>(
      xt, wval, val_b, 256, 472, valt, om_b, omf, nullptr, nullptr);
  dcn_core2<<<dim3(1024, 4), 256, 0, stream>>>(valt, omf, dcnt);
  mfma_gemm<3, 0><<<dim3(4, 256), 256, 0, stream>>>(
      dcnt, woutp, outp_b, 256, 256, d1t, bn3_g, bn3_b, bn3_m, bn3_v);
  mfma_gemm<4, 0><<<dim3(12, 256), 256, 0, stream>>>(
      d1t, wpw1, pw1_b, 256, 768, p1t, nullptr, nullptr, nullptr, nullptr);
  mfma_gemm<0, 0><<<dim3(4, 256), 256, 0, stream>>>(
      p1t, wpw2, pw2_b, 768, 256, dt, nullptr, nullptr, nullptr, nullptr);

  // out = x + y2 + d
  fuse_out_k<<<dim3(64, 4, 4), 256, 0, stream>>>(x, y2t, dt, out);
}

// Round 5
// 211.651 us; speedup vs baseline: 13.5025x; 1.0016x over previous
//
#include <hip/hip_runtime.h>
#include <math.h>

typedef __attribute__((ext_vector_type(8))) __bf16 bf16x8;
typedef __attribute__((ext_vector_type(8))) unsigned short us8;
typedef __attribute__((ext_vector_type(4))) unsigned short us4;
typedef __attribute__((ext_vector_type(4))) float f32x4;
typedef __attribute__((ext_vector_type(4))) int i32x4;
typedef unsigned int uint32;

#define EPSV 1e-5f

__device__ __forceinline__ float silu_f(float v) { return v / (1.f + __expf(-v)); }

__device__ __forceinline__ unsigned short f2bf(float f) {
  uint32 u = __builtin_bit_cast(uint32, f);
  u += 0x7fffu + ((u >> 16) & 1u);   // RNE
  return (unsigned short)(u >> 16);
}
__device__ __forceinline__ float bf2f(unsigned short h) {
  uint32 u = ((uint32)h) << 16;
  return __builtin_bit_cast(float, u);
}

// async global->LDS DMA, 16B per lane. LDS dest must be wave-uniform base +
// lane*16 (our fragment-major layout is exactly that).
__device__ __forceinline__ void gl_lds16(const void* g, void* l) {
  __builtin_amdgcn_global_load_lds(
      (const __attribute__((address_space(1))) unsigned int*)g,
      (__attribute__((address_space(3))) unsigned int*)l, 16, 0, 0);
}

// ---------------------------------------------------------------------------
// NCHW f32 -> NHWC bf16 tokens (N,4096,256), via LDS transpose.
// ---------------------------------------------------------------------------
__global__ __launch_bounds__(256) void nchw_to_tok(const float* __restrict__ x,
                                                   unsigned short* __restrict__ xt) {
  __shared__ float lds[64][65];
  const int p0 = blockIdx.x * 64, c0 = blockIdx.y * 64, n = blockIdx.z;
  const int t = threadIdx.x;
  const int pp = t & 63, ccb = t >> 6;
  const float* xb = x + ((size_t)n * 256 + c0) * 4096 + p0;
#pragma unroll
  for (int i = 0; i < 16; i++) {
    int cc = ccb * 16 + i;
    lds[pp][cc] = xb[(size_t)cc * 4096 + pp];
  }
  __syncthreads();
#pragma unroll
  for (int i = 0; i < 2; i++) {
    int pp2 = (t >> 3) + i * 32;
    int c8 = (t & 7) * 8;
    us8 v;
#pragma unroll
    for (int j = 0; j < 8; j++) v[j] = f2bf(lds[pp2][c8 + j]);
    *(us8*)&xt[((size_t)(n * 4096 + p0 + pp2)) * 256 + c0 + c8] = v;
  }
}

// ---------------------------------------------------------------------------
// out = x + y2 + d  (tokens bf16 -> NCHW f32), via LDS transpose.
// ---------------------------------------------------------------------------
__global__ __launch_bounds__(256) void fuse_out_k(
    const float* __restrict__ x, const unsigned short* __restrict__ y2t,
    const unsigned short* __restrict__ dt, float* __restrict__ out) {
  __shared__ float lds[64][65];
  const int p0 = blockIdx.x * 64, c0 = blockIdx.y * 64, n = blockIdx.z;
  const int t = threadIdx.x;
#pragma unroll
  for (int i = 0; i < 2; i++) {
    int pp = (t >> 3) + i * 32;
    int c8 = (t & 7) * 8;
    size_t base = ((size_t)(n * 4096 + p0 + pp)) * 256 + c0 + c8;
    us8 a = *(const us8*)&y2t[base];
    us8 b = *(const us8*)&dt[base];
#pragma unroll
    for (int j = 0; j < 8; j++) lds[pp][c8 + j] = bf2f(a[j]) + bf2f(b[j]);
  }
  __syncthreads();
  const int pp2 = t & 63, ccb = t >> 6;
  const size_t nco = ((size_t)n * 256 + c0) * 4096 + p0;
#pragma unroll
  for (int i = 0; i < 16; i++) {
    int cc = ccb * 16 + i;
    size_t idx = nco + (size_t)cc * 4096 + pp2;
    out[idx] = x[idx] + lds[pp2][cc];
  }
}

// ---------------------------------------------------------------------------
// All weight conversions in ONE launch (+ zero-page init).
// conv weights: (Co,Ci,3,3) f32 -> (Co, 9*Ci) bf16 with k = tap*Ci + ci
// ---------------------------------------------------------------------------
__global__ void cvt_all(
    const float* __restrict__ c1, unsigned short* __restrict__ o1,
    const float* __restrict__ c2, unsigned short* __restrict__ o2,
    const float* __restrict__ a0, unsigned short* __restrict__ b0,
    const float* __restrict__ a1, unsigned short* __restrict__ b1,
    const float* __restrict__ a2, unsigned short* __restrict__ b2,
    const float* __restrict__ a3, unsigned short* __restrict__ b3,
    const float* __restrict__ a4, unsigned short* __restrict__ b4,
    uint32* __restrict__ zp) {
  if (blockIdx.x == 0 && threadIdx.x < 32) zp[threadIdx.x] = 0u;
  int idx = blockIdx.x * 256 + threadIdx.x;
  if (idx < 294912) {
    int ci = idx & 255, r = idx >> 8;
    int tap = r % 9, co = r / 9;
    o1[idx] = f2bf(c1[((size_t)co * 256 + ci) * 9 + tap]);
    return;
  }
  idx -= 294912;
  if (idx < 294912) {
    int ci = idx & 127, r = idx >> 7;
    int tap = r % 9, co = r / 9;
    o2[idx] = f2bf(c2[((size_t)co * 128 + ci) * 9 + tap]);
    return;
  }
  idx -= 294912;
  const float* s;
  unsigned short* d;
  int off;
  if (idx < 65536)       { s = a0; d = b0; off = idx; }
  else if (idx < 120832) { s = a1; d = b1; off = idx - 65536; }
  else if (idx < 186368) { s = a2; d = b2; off = idx - 120832; }
  else if (idx < 382976) { s = a3; d = b3; off = idx - 186368; }
  else if (idx < 579584) { s = a4; d = b4; off = idx - 382976; }
  else return;
  d[off] = f2bf(s[off]);
}

// ---------------------------------------------------------------------------
// Unified bf16 MFMA GEMM, 64x64 tile, 4 waves (each 32x32 out), BK=64,
// double-buffered LDS staged via global_load_lds (16B/lane), 2-phase
// schedule: issue next-tile DMA -> compute current -> one __syncthreads()
// (its vmcnt(0) drain is the counted wait for the in-flight loads).
//   A: tokens (16384, K) bf16; CONV (CIN>0): K = 9*CIN, implicit im2col;
//      OOB taps / cols read a 64B zero page.
//   B: (Co, K) bf16 row-major.
// LDS fragment-major: chunk id = ((sub*2+ks)*64 + kg*16 + idx16); stage
// writes and frag reads are lane-linear 1024B sweeps (conflict-free, and
// exactly the wave-uniform-base + lane*16 pattern global_load_lds needs).
// EPI: 0 = bias->bf16 | 1 = bias->f32 | 2 = BN+SiLU->bf16 (no bias)
//      3 = bias+BN->bf16 | 4 = bias+SiLU->bf16
//      5 = split val/om: col<256 -> bf16 outv (stride 256, bias=bias);
//          col>=256  -> f32 (float*)e1 (stride 216, bias=e0[col-256])
// ---------------------------------------------------------------------------
template <int EPI, int CIN>
__global__ __launch_bounds__(256) void mfma_gemm(
    const unsigned short* __restrict__ A, const unsigned short* __restrict__ Bw,
    const float* __restrict__ bias, int K, int Co, void* __restrict__ outv,
    const float* __restrict__ e0, const float* __restrict__ e1,
    const float* __restrict__ e2, const float* __restrict__ e3,
    const unsigned short* __restrict__ zpage) {
  __shared__ bf16x8 smem[2048];  // [buf:2][A 512 | B 512 chunks] = 32 KB
  const int t = threadIdx.x;
  const int lane = t & 63;
  const int wv = t >> 6;
  const int wr = wv >> 1, wc = wv & 1;
  const int rb = blockIdx.y * 64, cb = blockIdx.x * 64;

  f32x4 acc[2][2];
#pragma unroll
  for (int i = 0; i < 2; i++)
#pragma unroll
    for (int j = 0; j < 2; j++) acc[i][j] = (f32x4){0.f, 0.f, 0.f, 0.f};

  auto addrA = [&](int c, int kb) -> const unsigned short* {
    int row16 = c & 15, kg = (c >> 4) & 3, ks = (c >> 6) & 1, msub = c >> 7;
    int row = msub * 16 + row16;
    int koff = ks * 32 + kg * 8;
    if constexpr (CIN > 0) {
      int tap = kb / CIN, ci = kb % CIN + koff;
      int dy = tap / 3 - 1, dx = tap % 3 - 1;
      int grow = rb + row;
      int n = grow >> 12, p = grow & 4095;
      int h = (p >> 6) + dy, w = (p & 63) + dx;
      if (((unsigned)h < 64u) && ((unsigned)w < 64u))
        return &A[((size_t)(n * 4096 + h * 64 + w)) * CIN + ci];
      return zpage;
    } else {
      return &A[(size_t)(rb + row) * K + kb + koff];
    }
  };
  auto addrB = [&](int c, int kb) -> const unsigned short* {
    int col16 = c & 15, kg = (c >> 4) & 3, ks = (c >> 6) & 1, csub = c >> 7;
    int col = cb + csub * 16 + col16;
    int koff = ks * 32 + kg * 8;
    return (col < Co) ? &Bw[(size_t)col * K + kb + koff] : zpage;
  };
  auto stage = [&](int buf, int kb) {
    bf16x8* base = &smem[buf * 1024];
    gl_lds16(addrA(t, kb), (void*)&base[t]);
    gl_lds16(addrA(t + 256, kb), (void*)&base[t + 256]);
    gl_lds16(addrB(t, kb), (void*)&base[512 + t]);
    gl_lds16(addrB(t + 256, kb), (void*)&base[512 + t + 256]);
  };

  const int nt = K >> 6;
  stage(0, 0);
  __syncthreads();
  int cur = 0;
  for (int it = 0; it < nt; ++it) {
    if (it + 1 < nt) stage(cur ^ 1, (it + 1) << 6);
    const bf16x8* Ab = &smem[cur * 1024];
    const bf16x8* Bb = Ab + 512;
    __builtin_amdgcn_s_setprio(1);
#pragma unroll
    for (int ks = 0; ks < 2; ks++) {
      bf16x8 af[2], bfr[2];
#pragma unroll
      for (int mi = 0; mi < 2; mi++) af[mi] = Ab[((wr * 2 + mi) * 2 + ks) * 64 + lane];
#pragma unroll
      for (int ni = 0; ni < 2; ni++) bfr[ni] = Bb[((wc * 2 + ni) * 2 + ks) * 64 + lane];
#pragma unroll
      for (int mi = 0; mi < 2; mi++)
#pragma unroll
        for (int ni = 0; ni < 2; ni++)
          acc[mi][ni] = __builtin_amdgcn_mfma_f32_16x16x32_bf16(af[mi], bfr[ni],
                                                                acc[mi][ni], 0, 0, 0);
    }
    __builtin_amdgcn_s_setprio(0);
    __syncthreads();   // drains vmcnt(0): next tile's DMA is complete
    cur ^= 1;
  }

  // ---- epilogue.  C/D: col = lane&15, row = (lane>>4)*4 + reg
  const int lr = lane & 15, kg4 = (lane >> 4) * 4;
#pragma unroll
  for (int mi = 0; mi < 2; mi++) {
#pragma unroll
    for (int ni = 0; ni < 2; ni++) {
      int gcol = cb + wc * 32 + ni * 16 + lr;
      if (gcol >= Co) continue;
      float bval, s = 1.f, tt = 0.f;
      if (EPI == 2) bval = 0.f;
      else if (EPI == 5) bval = (gcol < 256) ? bias[gcol] : e0[gcol - 256];
      else bval = bias[gcol];
      if (EPI == 2 || EPI == 3) {
        s = e0[gcol] * rsqrtf(e3[gcol] + EPSV);
        tt = e1[gcol] - e2[gcol] * s;
      }
#pragma unroll
      for (int j = 0; j < 4; j++) {
        int grow = rb + wr * 32 + mi * 16 + kg4 + j;
        float v = acc[mi][ni][j] + bval;
        if (EPI == 2) v = silu_f(v * s + tt);
        if (EPI == 3) v = v * s + tt;
        if (EPI == 4) v = silu_f(v);
        if (EPI == 1) {
          ((float*)outv)[(size_t)grow * Co + gcol] = v;
        } else if (EPI == 5) {
          if (gcol < 256)
            ((unsigned short*)outv)[(size_t)grow * 256 + gcol] = f2bf(v);
          else
            ((float*)e1)[(size_t)grow * 216 + (gcol - 256)] = v;
        } else {
          ((unsigned short*)outv)[(size_t)grow * Co + gcol] = f2bf(v);
        }
      }
    }
  }
}

// ---------------------------------------------------------------------------
// DCNv4 core v2 (two-phase).  value: bf16 tokens (N,4096,256),
// om: f32 tokens (N,4096,216), out: bf16 tokens.
// ---------------------------------------------------------------------------
__global__ __launch_bounds__(256) void dcn_core2(
    const unsigned short* __restrict__ value, const float* __restrict__ om,
    unsigned short* __restrict__ out) {
  __shared__ f32x4 wgt[288];
  __shared__ i32x4 adr[288];
  const int n = blockIdx.y;
  const int p0 = blockIdx.x * 4;
  const int t = threadIdx.x;

  for (int idx = t; idx < 288; idx += 256) {
    int pi = idx / 72;
    int gk = idx - pi * 72;
    int g = gk / 9, k = gk - g * 9;
    int p = p0 + pi;
    int h0 = p >> 6, w0 = p & 63;
    const float* omp = om + ((size_t)(n * 4096 + p)) * 216 + g * 27;
    float ox = omp[2 * k], oy = omp[2 * k + 1], mk = omp[18 + k];
    float px = (float)(w0 + (k % 3) - 1) + ox;
    float py = (float)(h0 + (k / 3) - 1) + oy;
    float x0f = floorf(px), y0f = floorf(py);
    float lx = px - x0f, ly = py - y0f;
    int x0 = (int)x0f, y0 = (int)y0f;
    int x1 = x0 + 1, y1 = y0 + 1;
    bool vx0 = (unsigned)x0 < 64u, vx1 = (unsigned)x1 < 64u;
    bool vy0 = (unsigned)y0 < 64u, vy1 = (unsigned)y1 < 64u;
    int cx0 = min(max(x0, 0), 63), cx1 = min(max(x1, 0), 63);
    int cy0 = min(max(y0, 0), 63), cy1 = min(max(y1, 0), 63);
    f32x4 w4;
    w4[0] = (1.f - ly) * (1.f - lx) * mk * (float)(vy0 && vx0);
    w4[1] = (1.f - ly) * lx * mk * (float)(vy0 && vx1);
    w4[2] = ly * (1.f - lx) * mk * (float)(vy1 && vx0);
    w4[3] = ly * lx * mk * (float)(vy1 && vx1);
    i32x4 a4;
    a4[0] = (cy0 * 64 + cx0) * 256;
    a4[1] = (cy0 * 64 + cx1) * 256;
    a4[2] = (cy1 * 64 + cx0) * 256;
    a4[3] = (cy1 * 64 + cx1) * 256;
    wgt[idx] = w4;
    adr[idx] = a4;
  }
  __syncthreads();

  const int pi = t >> 6;
  const int g = (t >> 3) & 7;
  const int l = t & 7;
  const int p = p0 + pi;
  const unsigned short* vb = value + ((size_t)n * 4096) * 256 + g * 32 + l * 4;
  const int bix = (pi * 8 + g) * 9;
  float a0 = 0.f, a1 = 0.f, a2 = 0.f, a3 = 0.f;
#pragma unroll
  for (int k = 0; k < 9; k++) {
    f32x4 wv = wgt[bix + k];
    i32x4 av = adr[bix + k];
    us4 q0 = *(const us4*)(vb + av[0]);
    us4 q1 = *(const us4*)(vb + av[1]);
    us4 q2 = *(const us4*)(vb + av[2]);
    us4 q3 = *(const us4*)(vb + av[3]);
    a0 += wv[0] * bf2f(q0[0]) + wv[1] * bf2f(q1[0]) + wv[2] * bf2f(q2[0]) + wv[3] * bf2f(q3[0]);
    a1 += wv[0] * bf2f(q0[1]) + wv[1] * bf2f(q1[1]) + wv[2] * bf2f(q2[1]) + wv[3] * bf2f(q3[1]);
    a2 += wv[0] * bf2f(q0[2]) + wv[1] * bf2f(q1[2]) + wv[2] * bf2f(q2[2]) + wv[3] * bf2f(q3[2]);
    a3 += wv[0] * bf2f(q0[3]) + wv[1] * bf2f(q1[3]) + wv[2] * bf2f(q2[3]) + wv[3] * bf2f(q3[3]);
  }
  us4 o;
  o[0] = f2bf(a0); o[1] = f2bf(a1); o[2] = f2bf(a2); o[3] = f2bf(a3);
  *(us4*)&out[((size_t)(n * 4096 + p)) * 256 + g * 32 + l * 4] = o;
}

// ---------------------------------------------------------------------------
extern "C" void kernel_launch(void* const* d_in, const int* in_sizes, int n_in,
                              void* d_out, int out_size, void* d_ws,
                              size_t ws_size, hipStream_t stream) {
  const float* x      = (const float*)d_in[0];
  const float* cv1_w  = (const float*)d_in[1];
  const float* cv1_g  = (const float*)d_in[2];
  const float* cv1_b  = (const float*)d_in[3];
  const float* cv1_m  = (const float*)d_in[4];
  const float* cv1_v  = (const float*)d_in[5];
  const float* cv2_w  = (const float*)d_in[6];
  const float* cv2_g  = (const float*)d_in[7];
  const float* cv2_b  = (const float*)d_in[8];
  const float* cv2_m  = (const float*)d_in[9];
  const float* cv2_v  = (const float*)d_in[10];
  const float* val_w  = (const float*)d_in[11];
  const float* val_b  = (const float*)d_in[12];
  const float* om_w   = (const float*)d_in[13];
  const float* om_b   = (const float*)d_in[14];
  const float* outp_w = (const float*)d_in[15];
  const float* outp_b = (const float*)d_in[16];
  const float* bn3_g  = (const float*)d_in[17];
  const float* bn3_b  = (const float*)d_in[18];
  const float* bn3_m  = (const float*)d_in[19];
  const float* bn3_v  = (const float*)d_in[20];
  const float* pw1_w  = (const float*)d_in[21];
  const float* pw1_b  = (const float*)d_in[22];
  const float* pw2_w  = (const float*)d_in[23];
  const float* pw2_b  = (const float*)d_in[24];
  float* out = (float*)d_out;

  char* w = (char*)d_ws;
  auto alloc = [&](size_t bytes) {
    char* p = w;
    w += (bytes + 255) & ~(size_t)255;
    return p;
  };
  unsigned short* xt    = (unsigned short*)alloc(16384ull * 256 * 2);
  unsigned short* y1t   = (unsigned short*)alloc(16384ull * 128 * 2);
  unsigned short* y2t   = (unsigned short*)alloc(16384ull * 256 * 2);
  unsigned short* valt  = (unsigned short*)alloc(16384ull * 256 * 2);
  float*          omf   = (float*)alloc(16384ull * 216 * 4);
  unsigned short* dcnt  = (unsigned short*)alloc(16384ull * 256 * 2);
  unsigned short* d1t   = (unsigned short*)alloc(16384ull * 256 * 2);
  unsigned short* p1t   = (unsigned short*)alloc(16384ull * 768 * 2);
  unsigned short* dt    = (unsigned short*)alloc(16384ull * 256 * 2);
  unsigned short* wc1   = (unsigned short*)alloc(128ull * 2304 * 2);
  unsigned short* wc2   = (unsigned short*)alloc(256ull * 1152 * 2);
  // wval and wom MUST be contiguous (fused val/om GEMM B-matrix, 472 x 256):
  unsigned short* wval  = (unsigned short*)alloc(256ull * 256 * 2);   // 256-mult
  unsigned short* wom   = (unsigned short*)alloc(216ull * 256 * 2);   // = wval + 65536
  unsigned short* woutp = (unsigned short*)alloc(256ull * 256 * 2);
  unsigned short* wpw1  = (unsigned short*)alloc(768ull * 256 * 2);
  unsigned short* wpw2  = (unsigned short*)alloc(256ull * 768 * 2);
  unsigned short* zpage = (unsigned short*)alloc(256);  // 64B zeros (+pad)

  // conversions (2 launches)
  nchw_to_tok<<<dim3(64, 4, 4), 256, 0, stream>>>(x, xt);
  cvt_all<<<4568, 256, 0, stream>>>(cv1_w, wc1, cv2_w, wc2, val_w, wval, om_w, wom,
                                    outp_w, woutp, pw1_w, wpw1, pw2_w, wpw2,
                                    (uint32*)zpage);

  // y path (convs as implicit GEMM)
  mfma_gemm<2, 256><<<dim3(2, 256), 256, 0, stream>>>(
      xt, wc1, nullptr, 2304, 128, y1t, cv1_g, cv1_b, cv1_m, cv1_v, zpage);
  mfma_gemm<2, 128><<<dim3(4, 256), 256, 0, stream>>>(
      y1t, wc2, nullptr, 1152, 256, y2t, cv2_g, cv2_b, cv2_m, cv2_v, zpage);

  // dcn path: fused val+om projection (B rows 0-255 = val_w, 256-471 = om_w)
  mfma_gemm<5, 0><<<dim3(8, 256), 256, 0, stream>>>(
      xt, wval, val_b, 256, 472, valt, om_b, omf, nullptr, nullptr, zpage);
  dcn_core2<<<dim3(1024, 4), 256, 0, stream>>>(valt, omf, dcnt);
  mfma_gemm<3, 0><<<dim3(4, 256), 256, 0, stream>>>(
      dcnt, woutp, outp_b, 256, 256, d1t, bn3_g, bn3_b, bn3_m, bn3_v, zpage);
  mfma_gemm<4, 0><<<dim3(12, 256), 256, 0, stream>>>(
      d1t, wpw1, pw1_b, 256, 768, p1t, nullptr, nullptr, nullptr, nullptr, zpage);
  mfma_gemm<0, 0><<<dim3(4, 256), 256, 0, stream>>>(
      p1t, wpw2, pw2_b, 768, 256, dt, nullptr, nullptr, nullptr, nullptr, zpage);

  // out = x + y2 + d
  fuse_out_k<<<dim3(64, 4, 4), 256, 0, stream>>>(x, y2t, dt, out);
}